// Round 1
// baseline (367.852 us; speedup 1.0000x reference)
//
#include <hip/hip_runtime.h>
#include <hip/hip_bf16.h>
#include <math.h>

// Problem constants (B=4, S=2048, D=1024, H=2048, E=8)
#define M_TOK 8192   // B*S
#define N_H   2048   // H
#define K_D   1024   // D
#define N_E   8

typedef __bf16 bf16x8 __attribute__((ext_vector_type(8)));
typedef __bf16 bf16x4 __attribute__((ext_vector_type(4)));
typedef float  f32x4  __attribute__((ext_vector_type(4)));

__device__ inline f32x4 mfma16(bf16x8 a, bf16x8 b, f32x4 c) {
  return __builtin_amdgcn_mfma_f32_16x16x32_bf16(a, b, c, 0, 0, 0);
}

__device__ inline void load16_lds(const void* g, void* l) {
  __builtin_amdgcn_global_load_lds(
      (const __attribute__((address_space(1))) void*)g,
      (__attribute__((address_space(3))) void*)l, 16, 0, 0);
}

// ---------------------------------------------------------------- f32 -> bf16
__global__ __launch_bounds__(256) void cvt_kernel(const float* __restrict__ src,
                                                  __bf16* __restrict__ dst,
                                                  int n4) {
  int i = blockIdx.x * blockDim.x + threadIdx.x;
  const int stride = gridDim.x * blockDim.x;
  for (; i < n4; i += stride) {
    float4 v = ((const float4*)src)[i];
    bf16x4 o = {(__bf16)v.x, (__bf16)v.y, (__bf16)v.z, (__bf16)v.w};
    *(bf16x4*)(dst + (size_t)i * 4) = o;
  }
}

// ------------------------------------------------------------------ gate probs
// One wave per token: 8 dots of length 1024, xor-reduce, softmax over E=8.
__global__ __launch_bounds__(256) void gate_kernel(const float* __restrict__ X,
                                                   const float* __restrict__ Wg,
                                                   const float* __restrict__ bg,
                                                   float* __restrict__ gate) {
  const int tid = threadIdx.x;
  const int lane = tid & 63;
  const int wv = tid >> 6;
  const int token = blockIdx.x * 4 + wv;
  const float* xrow = X + (size_t)token * K_D;

  float xr[16];
#pragma unroll
  for (int i = 0; i < 16; ++i) xr[i] = xrow[lane + i * 64];

  float l[N_E];
#pragma unroll
  for (int e = 0; e < N_E; ++e) {
    const float* wrow = Wg + e * K_D;
    float s = 0.f;
#pragma unroll
    for (int i = 0; i < 16; ++i) s += xr[i] * wrow[lane + i * 64];
#pragma unroll
    for (int off = 32; off > 0; off >>= 1) s += __shfl_xor(s, off);
    l[e] = s + bg[e];
  }
  float mx = l[0];
#pragma unroll
  for (int e = 1; e < N_E; ++e) mx = fmaxf(mx, l[e]);
  float p[N_E], den = 0.f;
#pragma unroll
  for (int e = 0; e < N_E; ++e) { p[e] = expf(l[e] - mx); den += p[e]; }
  const float inv = 1.f / den;
  if (lane == 0) {
#pragma unroll
    for (int e = 0; e < N_E; ++e) gate[(size_t)token * N_E + e] = p[e] * inv;
  }
}

// ------------------------------------------------------------------- main MoE
// 128x128 output tile, 4 waves (2x2), each wave 4x4 frags of 16x16x32 bf16 MFMA.
// For each expert: full K=1024 GEMM accumulation, then
//   fin += gate[row][e] * leaky_relu(acc + be[e][col]).
__global__ __launch_bounds__(256, 2) void moe_main(
    const __bf16* __restrict__ Xb, const __bf16* __restrict__ Wb,
    const float* __restrict__ gate, const float* __restrict__ be,
    float* __restrict__ out) {
  __shared__ __bf16 As[128 * 32];   // [row][k] 8 KB
  __shared__ __bf16 Bs[128 * 32];   // [col][k] 8 KB
  __shared__ float gS[128 * 8];     // [row][e] 4 KB
  __shared__ float bS[8 * 128];     // [e][col] 4 KB

  const int tid = threadIdx.x;
  const int lane = tid & 63;
  const int wv = tid >> 6;
  const int wr = wv >> 1, wc = wv & 1;
  const int row0 = blockIdx.x * 128;
  const int col0 = blockIdx.y * 128;

  // Preload gate/be tiles (first __syncthreads below publishes them).
  for (int i = tid; i < 1024; i += 256) {
    gS[i] = gate[(size_t)row0 * N_E + i];
    bS[i] = be[(size_t)(i >> 7) * N_H + col0 + (i & 127)];
  }

  // Staging geometry: thread tid stages 16B (8 bf16) at tile row rA, k kk.
  const int rA = tid >> 2;
  const int kk = (tid & 3) * 8;
  const __bf16* aP0 = Xb + (size_t)(row0 + rA) * K_D + kk;
  const __bf16* aP1 = aP0 + (size_t)64 * K_D;

  // Fragment read addresses.
  const int lr = lane & 15;
  const int lk = (lane >> 4) * 8;
  const __bf16* aRd = &As[(wr * 64 + lr) * 32 + lk];
  const __bf16* bRd = &Bs[(wc * 64 + lr) * 32 + lk];

  f32x4 fin[4][4];
#pragma unroll
  for (int m = 0; m < 4; ++m)
#pragma unroll
    for (int n = 0; n < 4; ++n) fin[m][n] = (f32x4){0.f, 0.f, 0.f, 0.f};

  for (int e = 0; e < N_E; ++e) {
    const __bf16* bP0 =
        Wb + (size_t)e * N_H * K_D + (size_t)(col0 + rA) * K_D + kk;
    const __bf16* bP1 = bP0 + (size_t)64 * K_D;

    f32x4 acc[4][4];
#pragma unroll
    for (int m = 0; m < 4; ++m)
#pragma unroll
      for (int n = 0; n < 4; ++n) acc[m][n] = (f32x4){0.f, 0.f, 0.f, 0.f};

    for (int kt = 0; kt < K_D / 32; ++kt) {
      const int k0 = kt * 32;
      __syncthreads();  // previous tile consumed (also publishes gS/bS at e=0,kt=0)
      load16_lds(aP0 + k0, &As[wv * 512]);
      load16_lds(aP1 + k0, &As[2048 + wv * 512]);
      load16_lds(bP0 + k0, &Bs[wv * 512]);
      load16_lds(bP1 + k0, &Bs[2048 + wv * 512]);
      __syncthreads();  // vmcnt(0) drain: staged tile visible

      bf16x8 af[4], bfr[4];
#pragma unroll
      for (int m = 0; m < 4; ++m) af[m] = *(const bf16x8*)(aRd + m * 16 * 32);
#pragma unroll
      for (int n = 0; n < 4; ++n) bfr[n] = *(const bf16x8*)(bRd + n * 16 * 32);
#pragma unroll
      for (int m = 0; m < 4; ++m)
#pragma unroll
        for (int n = 0; n < 4; ++n)
          acc[m][n] = mfma16(af[m], bfr[n], acc[m][n]);
    }

    // Per-expert epilogue: fin += gate * leaky_relu(acc + be)
#pragma unroll
    for (int m = 0; m < 4; ++m) {
#pragma unroll
      for (int j = 0; j < 4; ++j) {
        const int r = wr * 64 + m * 16 + (lane >> 4) * 4 + j;
        const float g = gS[r * 8 + e];
#pragma unroll
        for (int n = 0; n < 4; ++n) {
          float v = acc[m][n][j] + bS[e * 128 + wc * 64 + n * 16 + lr];
          v = (v >= 0.f) ? v : 0.01f * v;
          fin[m][n][j] += g * v;
        }
      }
    }
  }

  // C write (fp32 out)
#pragma unroll
  for (int m = 0; m < 4; ++m) {
#pragma unroll
    for (int j = 0; j < 4; ++j) {
      const size_t r = (size_t)(row0 + wr * 64 + m * 16 + (lane >> 4) * 4 + j);
#pragma unroll
      for (int n = 0; n < 4; ++n) {
        out[r * N_H + col0 + wc * 64 + n * 16 + lr] = fin[m][n][j];
      }
    }
  }
}

extern "C" void kernel_launch(void* const* d_in, const int* in_sizes, int n_in,
                              void* d_out, int out_size, void* d_ws, size_t ws_size,
                              hipStream_t stream) {
  const float* X  = (const float*)d_in[0];  // [8192,1024]
  const float* Wg = (const float*)d_in[1];  // [8,1024]
  const float* bg = (const float*)d_in[2];  // [8]
  const float* We = (const float*)d_in[3];  // [8,2048,1024]
  const float* be = (const float*)d_in[4];  // [8,2048]
  float* out = (float*)d_out;               // [8192,2048]

  // Workspace layout
  char* ws = (char*)d_ws;
  __bf16* Xb   = (__bf16*)(ws);                               // 16 MB
  __bf16* Wb   = (__bf16*)(ws + (size_t)16 * 1024 * 1024);    // 32 MB
  float*  gate = (float*)(ws + (size_t)48 * 1024 * 1024);     // 256 KB

  // 1) f32 -> bf16 conversions
  cvt_kernel<<<2048, 256, 0, stream>>>(X, Xb, (M_TOK * K_D) / 4);
  cvt_kernel<<<2048, 256, 0, stream>>>(We, Wb, (N_E * N_H * K_D) / 4);

  // 2) gate probs
  gate_kernel<<<M_TOK / 4, 256, 0, stream>>>(X, Wg, bg, gate);

  // 3) fused expert GEMM + gate-weighted reduction
  dim3 grid(M_TOK / 128, N_H / 128);
  moe_main<<<grid, 256, 0, stream>>>(Xb, Wb, gate, be, out);
}

// Round 3
// 331.937 us; speedup vs baseline: 1.1082x; 1.1082x over previous
//
#include <hip/hip_runtime.h>
#include <hip/hip_bf16.h>
#include <math.h>

// Problem constants (B=4, S=2048, D=1024, H=2048, E=8)
#define M_TOK 8192   // B*S
#define N_H   2048   // H
#define K_D   1024   // D
#define N_E   8

typedef __bf16 bf16x8 __attribute__((ext_vector_type(8)));
typedef __bf16 bf16x4 __attribute__((ext_vector_type(4)));
typedef float  f32x4  __attribute__((ext_vector_type(4)));

__device__ inline f32x4 mfma16(bf16x8 a, bf16x8 b, f32x4 c) {
  return __builtin_amdgcn_mfma_f32_16x16x32_bf16(a, b, c, 0, 0, 0);
}

__device__ inline void load16_lds(const void* g, void* l) {
  __builtin_amdgcn_global_load_lds(
      (const __attribute__((address_space(1))) void*)g,
      (__attribute__((address_space(3))) void*)l, 16, 0, 0);
}

// ---------------------------------------------------------------- f32 -> bf16
__global__ __launch_bounds__(256) void cvt_kernel(const float* __restrict__ src,
                                                  __bf16* __restrict__ dst,
                                                  int n4) {
  int i = blockIdx.x * blockDim.x + threadIdx.x;
  const int stride = gridDim.x * blockDim.x;
  for (; i < n4; i += stride) {
    float4 v = ((const float4*)src)[i];
    bf16x4 o = {(__bf16)v.x, (__bf16)v.y, (__bf16)v.z, (__bf16)v.w};
    *(bf16x4*)(dst + (size_t)i * 4) = o;
  }
}

// ------------------------------------------------------------------ gate probs
__global__ __launch_bounds__(256) void gate_kernel(const float* __restrict__ X,
                                                   const float* __restrict__ Wg,
                                                   const float* __restrict__ bg,
                                                   float* __restrict__ gate) {
  const int tid = threadIdx.x;
  const int lane = tid & 63;
  const int wv = tid >> 6;
  const int token = blockIdx.x * 4 + wv;
  const float* xrow = X + (size_t)token * K_D;

  float xr[16];
#pragma unroll
  for (int i = 0; i < 16; ++i) xr[i] = xrow[lane + i * 64];

  float l[N_E];
#pragma unroll
  for (int e = 0; e < N_E; ++e) {
    const float* wrow = Wg + e * K_D;
    float s = 0.f;
#pragma unroll
    for (int i = 0; i < 16; ++i) s += xr[i] * wrow[lane + i * 64];
#pragma unroll
    for (int off = 32; off > 0; off >>= 1) s += __shfl_xor(s, off);
    l[e] = s + bg[e];
  }
  float mx = l[0];
#pragma unroll
  for (int e = 1; e < N_E; ++e) mx = fmaxf(mx, l[e]);
  float p[N_E], den = 0.f;
#pragma unroll
  for (int e = 0; e < N_E; ++e) { p[e] = expf(l[e] - mx); den += p[e]; }
  const float inv = 1.f / den;
  if (lane == 0) {
#pragma unroll
    for (int e = 0; e < N_E; ++e) gate[(size_t)token * N_E + e] = p[e] * inv;
  }
}

// ------------------------------------------------------------------- main MoE
// Block tile: 128 tokens x 128 h-cols, looping over 4 expert PAIRS.
// 4 waves (wr: token-half, wn: h-half). Wave tile: 64 tokens x (64 h x 2 experts)
//   -> acc[4][8] (128 regs), 32 MFMA per k-step vs 12 ds_read_b128 (384 B/MFMA,
//      MFMA-bound by design vs round-1's 512 B/MFMA).
// Linear LDS layout + round-1's proven 2-barrier schedule (no swizzle — the
// round-2 swizzle raced post-timing and was timing-neutral; reverted).
__global__ __launch_bounds__(256, 2) void moe_main(
    const __bf16* __restrict__ Xb, const __bf16* __restrict__ Wb,
    const float* __restrict__ gate, const float* __restrict__ be,
    float* __restrict__ out) {
  __shared__ __bf16 As[128 * 32];   // [token_row][k] 8 KB
  __shared__ __bf16 Bs[256 * 32];   // [(e01*128)+h_col][k] 16 KB (2 experts)
  __shared__ float gS[128 * 8];     // [token_row][e] 4 KB (all 8 experts)
  __shared__ float bS[8 * 128];     // [e][h_col] 4 KB (all 8 experts)

  const int tid = threadIdx.x;
  const int lane = tid & 63;
  const int wv = tid >> 6;
  const int wr = wv >> 1, wn = wv & 1;
  const int row0 = blockIdx.x * 128;
  const int col0 = blockIdx.y * 128;

  // Preload gate/be tiles (first __syncthreads in k-loop publishes them).
  for (int i = tid; i < 1024; i += 256) {
    gS[i] = gate[(size_t)row0 * N_E + i];
    bS[i] = be[(size_t)(i >> 7) * N_H + col0 + (i & 127)];
  }

  // Staging geometry: thread stages 16B chunks; row rA = tid>>2, chunk tid&3.
  const int rA = tid >> 2;
  const int kk = (tid & 3) * 8;
  const __bf16* aP0 = Xb + (size_t)(row0 + rA) * K_D + kk;
  const __bf16* aP1 = aP0 + (size_t)64 * K_D;

  // Fragment read addresses (linear, round-1 pattern).
  const int lr = lane & 15;
  const int lk = (lane >> 4) * 8;
  const __bf16* aRd = &As[(wr * 64 + lr) * 32 + lk];
  const __bf16* bRd = &Bs[(wn * 64 + lr) * 32 + lk];

  f32x4 fin[4][4];
#pragma unroll
  for (int m = 0; m < 4; ++m)
#pragma unroll
    for (int h = 0; h < 4; ++h) fin[m][h] = (f32x4){0.f, 0.f, 0.f, 0.f};

  for (int p = 0; p < 4; ++p) {
    const int e0 = p * 2;

    // B source pointers: Bs row q*64 + rA -> expert e0+(q>>1), h col0+(q&1)*64+rA
    const __bf16* bP0 = Wb + ((size_t)(e0 + 0) * N_H + col0 + 0  + rA) * K_D + kk;
    const __bf16* bP1 = Wb + ((size_t)(e0 + 0) * N_H + col0 + 64 + rA) * K_D + kk;
    const __bf16* bP2 = Wb + ((size_t)(e0 + 1) * N_H + col0 + 0  + rA) * K_D + kk;
    const __bf16* bP3 = Wb + ((size_t)(e0 + 1) * N_H + col0 + 64 + rA) * K_D + kk;

    f32x4 acc[4][8];
#pragma unroll
    for (int m = 0; m < 4; ++m)
#pragma unroll
      for (int n = 0; n < 8; ++n) acc[m][n] = (f32x4){0.f, 0.f, 0.f, 0.f};

    for (int kt = 0; kt < K_D / 32; ++kt) {
      const int k0 = kt * 32;
      __syncthreads();  // previous tile consumed (also publishes gS/bS first time)
      load16_lds(aP0 + k0, &As[wv * 512]);
      load16_lds(aP1 + k0, &As[2048 + wv * 512]);
      load16_lds(bP0 + k0, &Bs[wv * 512]);
      load16_lds(bP1 + k0, &Bs[2048 + wv * 512]);
      load16_lds(bP2 + k0, &Bs[4096 + wv * 512]);
      load16_lds(bP3 + k0, &Bs[6144 + wv * 512]);
      __syncthreads();  // staged tile visible

      bf16x8 af[4];
#pragma unroll
      for (int m = 0; m < 4; ++m) af[m] = *(const bf16x8*)(aRd + m * 16 * 32);
#pragma unroll
      for (int n = 0; n < 8; ++n) {
        const bf16x8 bfr =
            *(const bf16x8*)(bRd + ((n >> 2) * 128 + (n & 3) * 16) * 32);
#pragma unroll
        for (int m = 0; m < 4; ++m)
          acc[m][n] = mfma16(af[m], bfr, acc[m][n]);
      }
    }

    // Pair epilogue: fin += g_e0*LR(acc_e0 + be) + g_e1*LR(acc_e1 + be)
#pragma unroll
    for (int m = 0; m < 4; ++m) {
#pragma unroll
      for (int j = 0; j < 4; ++j) {
        const int r = wr * 64 + m * 16 + (lane >> 4) * 4 + j;
        const float g0 = gS[r * 8 + e0];
        const float g1 = gS[r * 8 + e0 + 1];
#pragma unroll
        for (int h = 0; h < 4; ++h) {
          const int c = wn * 64 + h * 16 + lr;
          float v0 = acc[m][h][j] + bS[e0 * 128 + c];
          v0 = (v0 >= 0.f) ? v0 : 0.01f * v0;
          float v1 = acc[m][4 + h][j] + bS[(e0 + 1) * 128 + c];
          v1 = (v1 >= 0.f) ? v1 : 0.01f * v1;
          fin[m][h][j] += g0 * v0 + g1 * v1;
        }
      }
    }
  }

  // C write (fp32 out)
#pragma unroll
  for (int m = 0; m < 4; ++m) {
#pragma unroll
    for (int j = 0; j < 4; ++j) {
      const size_t r = (size_t)(row0 + wr * 64 + m * 16 + (lane >> 4) * 4 + j);
#pragma unroll
      for (int h = 0; h < 4; ++h) {
        out[r * N_H + col0 + wn * 64 + h * 16 + lr] = fin[m][h][j];
      }
    }
  }
}

extern "C" void kernel_launch(void* const* d_in, const int* in_sizes, int n_in,
                              void* d_out, int out_size, void* d_ws, size_t ws_size,
                              hipStream_t stream) {
  const float* X  = (const float*)d_in[0];  // [8192,1024]
  const float* Wg = (const float*)d_in[1];  // [8,1024]
  const float* bg = (const float*)d_in[2];  // [8]
  const float* We = (const float*)d_in[3];  // [8,2048,1024]
  const float* be = (const float*)d_in[4];  // [8,2048]
  float* out = (float*)d_out;               // [8192,2048]

  // Workspace layout
  char* ws = (char*)d_ws;
  __bf16* Xb   = (__bf16*)(ws);                               // 16 MB
  __bf16* Wb   = (__bf16*)(ws + (size_t)16 * 1024 * 1024);    // 32 MB
  float*  gate = (float*)(ws + (size_t)48 * 1024 * 1024);     // 256 KB

  // 1) f32 -> bf16 conversions
  cvt_kernel<<<2048, 256, 0, stream>>>(X, Xb, (M_TOK * K_D) / 4);
  cvt_kernel<<<2048, 256, 0, stream>>>(We, Wb, (N_E * N_H * K_D) / 4);

  // 2) gate probs
  gate_kernel<<<M_TOK / 4, 256, 0, stream>>>(X, Wg, bg, gate);

  // 3) fused expert GEMM + gate-weighted reduction
  dim3 grid(M_TOK / 128, N_H / 128);
  moe_main<<<grid, 256, 0, stream>>>(Xb, Wb, gate, be, out);
}

// Round 4
// 314.215 us; speedup vs baseline: 1.1707x; 1.0564x over previous
//
#include <hip/hip_runtime.h>
#include <hip/hip_bf16.h>
#include <math.h>

// Problem constants (B=4, S=2048, D=1024, H=2048, E=8)
#define M_TOK 8192   // B*S
#define N_H   2048   // H
#define K_D   1024   // D
#define N_E   8

typedef __bf16 bf16x8 __attribute__((ext_vector_type(8)));
typedef __bf16 bf16x4 __attribute__((ext_vector_type(4)));
typedef float  f32x4  __attribute__((ext_vector_type(4)));

__device__ inline f32x4 mfma16(bf16x8 a, bf16x8 b, f32x4 c) {
  return __builtin_amdgcn_mfma_f32_16x16x32_bf16(a, b, c, 0, 0, 0);
}

__device__ inline void load16_lds(const void* g, void* l) {
  __builtin_amdgcn_global_load_lds(
      (const __attribute__((address_space(1))) void*)g,
      (__attribute__((address_space(3))) void*)l, 16, 0, 0);
}

// ---------------------------------------------------------------- f32 -> bf16
__global__ __launch_bounds__(256) void cvt_kernel(const float* __restrict__ src,
                                                  __bf16* __restrict__ dst,
                                                  int n4) {
  int i = blockIdx.x * blockDim.x + threadIdx.x;
  const int stride = gridDim.x * blockDim.x;
  for (; i < n4; i += stride) {
    float4 v = ((const float4*)src)[i];
    bf16x4 o = {(__bf16)v.x, (__bf16)v.y, (__bf16)v.z, (__bf16)v.w};
    *(bf16x4*)(dst + (size_t)i * 4) = o;
  }
}

// ------------------------------------------- gate probs + X f32->bf16 (fused)
__global__ __launch_bounds__(256) void gate_kernel(const float* __restrict__ X,
                                                   const float* __restrict__ Wg,
                                                   const float* __restrict__ bg,
                                                   float* __restrict__ gate,
                                                   __bf16* __restrict__ Xb) {
  const int tid = threadIdx.x;
  const int lane = tid & 63;
  const int wv = tid >> 6;
  const int token = blockIdx.x * 4 + wv;
  const float* xrow = X + (size_t)token * K_D;

  float xr[16];
#pragma unroll
  for (int i = 0; i < 16; ++i) xr[i] = xrow[lane + i * 64];

  // Fused bf16 conversion of X (coalesced 128B segments per i).
#pragma unroll
  for (int i = 0; i < 16; ++i)
    Xb[(size_t)token * K_D + lane + i * 64] = (__bf16)xr[i];

  float l[N_E];
#pragma unroll
  for (int e = 0; e < N_E; ++e) {
    const float* wrow = Wg + e * K_D;
    float s = 0.f;
#pragma unroll
    for (int i = 0; i < 16; ++i) s += xr[i] * wrow[lane + i * 64];
#pragma unroll
    for (int off = 32; off > 0; off >>= 1) s += __shfl_xor(s, off);
    l[e] = s + bg[e];
  }
  float mx = l[0];
#pragma unroll
  for (int e = 1; e < N_E; ++e) mx = fmaxf(mx, l[e]);
  float p[N_E], den = 0.f;
#pragma unroll
  for (int e = 0; e < N_E; ++e) { p[e] = expf(l[e] - mx); den += p[e]; }
  const float inv = 1.f / den;
  if (lane == 0) {
#pragma unroll
    for (int e = 0; e < N_E; ++e) gate[(size_t)token * N_E + e] = p[e] * inv;
  }
}

// ------------------------------------------------------------------- main MoE
// Block tile: 128 tokens x 128 h-cols, flat loop over 128 k-steps
// (4 expert-pairs x 32). 2-phase double-buffered LDS (T3-minimum recipe):
// per k-step: STAGE(t+1 -> buf^1) issued FIRST, then ds_read+MFMA on buf,
// then ONE __syncthreads (vmcnt(0)+barrier). Load latency overlaps compute.
// Staging geometry / linear LDS / epilogue identical to the verified r3 kernel.
__global__ __launch_bounds__(256, 2) void moe_main(
    const __bf16* __restrict__ Xb, const __bf16* __restrict__ Wb,
    const float* __restrict__ gate, const float* __restrict__ be,
    float* __restrict__ out) {
  __shared__ __bf16 As[2][128 * 32];   // 16 KB (double-buffered)
  __shared__ __bf16 Bs[2][256 * 32];   // 32 KB (double-buffered, 2 experts)
  __shared__ float gS[128 * 8];        // 4 KB
  __shared__ float bS[8 * 128];        // 4 KB

  const int tid = threadIdx.x;
  const int lane = tid & 63;
  const int wv = tid >> 6;
  const int wr = wv >> 1, wn = wv & 1;
  const int row0 = blockIdx.x * 128;
  const int col0 = blockIdx.y * 128;

  for (int i = tid; i < 1024; i += 256) {
    gS[i] = gate[(size_t)row0 * N_E + i];
    bS[i] = be[(size_t)(i >> 7) * N_H + col0 + (i & 127)];
  }

  // Staging geometry: thread stages 16B; LDS row rA = tid>>2, chunk tid&3.
  const int rA = tid >> 2;
  const int kk = (tid & 3) * 8;
  const __bf16* aB = Xb + (size_t)(row0 + rA) * K_D + kk;
  const __bf16* bB = Wb + (size_t)(col0 + rA) * K_D + kk;

  // Fragment read bases, one per buffer parity (compile-time selected).
  const int lr = lane & 15;
  const int lk = (lane >> 4) * 8;
  const __bf16* aRd0 = &As[0][(wr * 64 + lr) * 32 + lk];
  const __bf16* aRd1 = &As[1][(wr * 64 + lr) * 32 + lk];
  const __bf16* bRd0 = &Bs[0][(wn * 64 + lr) * 32 + lk];
  const __bf16* bRd1 = &Bs[1][(wn * 64 + lr) * 32 + lk];

  f32x4 fin[4][4];
#pragma unroll
  for (int m = 0; m < 4; ++m)
#pragma unroll
    for (int h = 0; h < 4; ++h) fin[m][h] = (f32x4){0.f, 0.f, 0.f, 0.f};

  f32x4 acc[4][8];
#pragma unroll
  for (int m = 0; m < 4; ++m)
#pragma unroll
    for (int n = 0; n < 8; ++n) acc[m][n] = (f32x4){0.f, 0.f, 0.f, 0.f};

  // Stage k-step tn into buffer bufN. tn = pair*32 + kt;
  // pair stride in Wb = 2 experts * N_H * K_D = 1<<22 elems.
  auto STAGE = [&](int tn, int bufN) {
    const int k0 = (tn & 31) << 5;
    const size_t pOff = (size_t)(tn >> 5) << 22;
    const __bf16* a = aB + k0;
    load16_lds(a, &As[bufN][wv * 512]);
    load16_lds(a + (size_t)64 * K_D, &As[bufN][2048 + wv * 512]);
    const __bf16* b = bB + pOff + k0;
    load16_lds(b, &Bs[bufN][wv * 512]);
    load16_lds(b + (size_t)64 * K_D, &Bs[bufN][2048 + wv * 512]);
    load16_lds(b + (size_t)N_H * K_D, &Bs[bufN][4096 + wv * 512]);
    load16_lds(b + (size_t)(N_H + 64) * K_D, &Bs[bufN][6144 + wv * 512]);
  };

  // Pair epilogue: fin += g_e0*LR(acc_e0 + be) + g_e1*LR(acc_e1 + be); acc=0.
  auto EPI = [&](int p) {
    const int e0 = p * 2;
#pragma unroll
    for (int m = 0; m < 4; ++m) {
#pragma unroll
      for (int j = 0; j < 4; ++j) {
        const int r = wr * 64 + m * 16 + (lane >> 4) * 4 + j;
        const float g0 = gS[r * 8 + e0];
        const float g1 = gS[r * 8 + e0 + 1];
#pragma unroll
        for (int h = 0; h < 4; ++h) {
          const int c = wn * 64 + h * 16 + lr;
          float v0 = acc[m][h][j] + bS[e0 * 128 + c];
          v0 = (v0 >= 0.f) ? v0 : 0.01f * v0;
          float v1 = acc[m][4 + h][j] + bS[(e0 + 1) * 128 + c];
          v1 = (v1 >= 0.f) ? v1 : 0.01f * v1;
          fin[m][h][j] += g0 * v0 + g1 * v1;
        }
      }
    }
#pragma unroll
    for (int m = 0; m < 4; ++m)
#pragma unroll
      for (int n = 0; n < 8; ++n) acc[m][n] = (f32x4){0.f, 0.f, 0.f, 0.f};
  };

  // One k-step at compile-time buffer parity.
  auto STEP = [&](int t, const __bf16* aRd, const __bf16* bRd, int nextBuf) {
    if (t < 127) STAGE(t + 1, nextBuf);  // issue early: latency hides under MFMA
    bf16x8 af[4];
#pragma unroll
    for (int m = 0; m < 4; ++m) af[m] = *(const bf16x8*)(aRd + m * 512);
    __builtin_amdgcn_s_setprio(1);
#pragma unroll
    for (int n = 0; n < 8; ++n) {
      const bf16x8 bfr =
          *(const bf16x8*)(bRd + ((n >> 2) * 128 + (n & 3) * 16) * 32);
#pragma unroll
      for (int m = 0; m < 4; ++m)
        acc[m][n] = mfma16(af[m], bfr, acc[m][n]);
    }
    __builtin_amdgcn_s_setprio(0);
    if ((t & 31) == 31) EPI(t >> 5);
    __syncthreads();  // vmcnt(0)+lgkmcnt(0)+barrier: next buffer ready
  };

  STAGE(0, 0);
  __syncthreads();  // prologue tile staged + gS/bS published

#pragma unroll 1
  for (int t2 = 0; t2 < 128; t2 += 2) {
    STEP(t2 + 0, aRd0, bRd0, 1);
    STEP(t2 + 1, aRd1, bRd1, 0);
  }

  // C write (fp32 out)
#pragma unroll
  for (int m = 0; m < 4; ++m) {
#pragma unroll
    for (int j = 0; j < 4; ++j) {
      const size_t r = (size_t)(row0 + wr * 64 + m * 16 + (lane >> 4) * 4 + j);
#pragma unroll
      for (int h = 0; h < 4; ++h) {
        out[r * N_H + col0 + wn * 64 + h * 16 + lr] = fin[m][h][j];
      }
    }
  }
}

extern "C" void kernel_launch(void* const* d_in, const int* in_sizes, int n_in,
                              void* d_out, int out_size, void* d_ws, size_t ws_size,
                              hipStream_t stream) {
  const float* X  = (const float*)d_in[0];  // [8192,1024]
  const float* Wg = (const float*)d_in[1];  // [8,1024]
  const float* bg = (const float*)d_in[2];  // [8]
  const float* We = (const float*)d_in[3];  // [8,2048,1024]
  const float* be = (const float*)d_in[4];  // [8,2048]
  float* out = (float*)d_out;               // [8192,2048]

  // Workspace layout
  char* ws = (char*)d_ws;
  __bf16* Xb   = (__bf16*)(ws);                               // 16 MB
  __bf16* Wb   = (__bf16*)(ws + (size_t)16 * 1024 * 1024);    // 32 MB
  float*  gate = (float*)(ws + (size_t)48 * 1024 * 1024);     // 256 KB

  // 1) We f32 -> bf16
  cvt_kernel<<<2048, 256, 0, stream>>>(We, Wb, (N_E * N_H * K_D) / 4);

  // 2) gate probs + X f32->bf16 (fused)
  gate_kernel<<<M_TOK / 4, 256, 0, stream>>>(X, Wg, bg, gate, Xb);

  // 3) fused expert GEMM + gate-weighted reduction
  dim3 grid(M_TOK / 128, N_H / 128);
  moe_main<<<grid, 256, 0, stream>>>(Xb, Wb, gate, be, out);
}

// Round 5
// 313.517 us; speedup vs baseline: 1.1733x; 1.0022x over previous
//
#include <hip/hip_runtime.h>
#include <hip/hip_bf16.h>
#include <math.h>

// Problem constants (B=4, S=2048, D=1024, H=2048, E=8)
#define M_TOK 8192   // B*S
#define N_H   2048   // H
#define K_D   1024   // D
#define N_E   8

typedef __bf16 bf16x8 __attribute__((ext_vector_type(8)));
typedef __bf16 bf16x4 __attribute__((ext_vector_type(4)));
typedef float  f32x4  __attribute__((ext_vector_type(4)));

__device__ inline f32x4 mfma16(bf16x8 a, bf16x8 b, f32x4 c) {
  return __builtin_amdgcn_mfma_f32_16x16x32_bf16(a, b, c, 0, 0, 0);
}

__device__ inline void load16_lds(const void* g, void* l) {
  __builtin_amdgcn_global_load_lds(
      (const __attribute__((address_space(1))) void*)g,
      (__attribute__((address_space(3))) void*)l, 16, 0, 0);
}

// ---------------------------------------------------------------- f32 -> bf16
__global__ __launch_bounds__(256) void cvt_kernel(const float* __restrict__ src,
                                                  __bf16* __restrict__ dst,
                                                  int n4) {
  int i = blockIdx.x * blockDim.x + threadIdx.x;
  const int stride = gridDim.x * blockDim.x;
  for (; i < n4; i += stride) {
    float4 v = ((const float4*)src)[i];
    bf16x4 o = {(__bf16)v.x, (__bf16)v.y, (__bf16)v.z, (__bf16)v.w};
    *(bf16x4*)(dst + (size_t)i * 4) = o;
  }
}

// ------------------------------------------- gate probs + X f32->bf16 (fused)
__global__ __launch_bounds__(256) void gate_kernel(const float* __restrict__ X,
                                                   const float* __restrict__ Wg,
                                                   const float* __restrict__ bg,
                                                   float* __restrict__ gate,
                                                   __bf16* __restrict__ Xb) {
  const int tid = threadIdx.x;
  const int lane = tid & 63;
  const int wv = tid >> 6;
  const int token = blockIdx.x * 4 + wv;
  const float* xrow = X + (size_t)token * K_D;

  float xr[16];
#pragma unroll
  for (int i = 0; i < 16; ++i) xr[i] = xrow[lane + i * 64];

#pragma unroll
  for (int i = 0; i < 16; ++i)
    Xb[(size_t)token * K_D + lane + i * 64] = (__bf16)xr[i];

  float l[N_E];
#pragma unroll
  for (int e = 0; e < N_E; ++e) {
    const float* wrow = Wg + e * K_D;
    float s = 0.f;
#pragma unroll
    for (int i = 0; i < 16; ++i) s += xr[i] * wrow[lane + i * 64];
#pragma unroll
    for (int off = 32; off > 0; off >>= 1) s += __shfl_xor(s, off);
    l[e] = s + bg[e];
  }
  float mx = l[0];
#pragma unroll
  for (int e = 1; e < N_E; ++e) mx = fmaxf(mx, l[e]);
  float p[N_E], den = 0.f;
#pragma unroll
  for (int e = 0; e < N_E; ++e) { p[e] = expf(l[e] - mx); den += p[e]; }
  const float inv = 1.f / den;
  if (lane == 0) {
#pragma unroll
    for (int e = 0; e < N_E; ++e) gate[(size_t)token * N_E + e] = p[e] * inv;
  }
}

// ------------------------------------------------------------------- main MoE
// Block tile: 128 tokens x 128 h-cols, flat loop over 128 k-steps
// (4 expert-pairs x 32). Tile/layout/epilogue identical to verified r4.
// NEW: T4 counted-vmcnt schedule (m201 phase order) — depth-2 prefetch,
// vmcnt(6) in steady state (never 0 in-loop), raw s_barrier (no implicit
// drain), lgkmcnt(0)+sched_barrier before the buffer-free barrier (rule 18).
// Per step t (buffer p = t&1):
//   vmcnt(6); barrier; ds_read 12 frags(buf p); lgkmcnt(0)+SGB(0); barrier;
//   STAGE(t+2 -> buf p); setprio(1); 32 MFMA; setprio(0); [EPI at t%32==31]
__global__ __launch_bounds__(256, 2) void moe_main(
    const __bf16* __restrict__ Xb, const __bf16* __restrict__ Wb,
    const float* __restrict__ gate, const float* __restrict__ be,
    float* __restrict__ out) {
  __shared__ __bf16 As[2][128 * 32];   // 16 KB (double-buffered)
  __shared__ __bf16 Bs[2][256 * 32];   // 32 KB (double-buffered, 2 experts)
  __shared__ float gS[128 * 8];        // 4 KB
  __shared__ float bS[8 * 128];        // 4 KB

  const int tid = threadIdx.x;
  const int lane = tid & 63;
  const int wv = tid >> 6;
  const int wr = wv >> 1, wn = wv & 1;
  const int row0 = blockIdx.x * 128;
  const int col0 = blockIdx.y * 128;

  for (int i = tid; i < 1024; i += 256) {
    gS[i] = gate[(size_t)row0 * N_E + i];
    bS[i] = be[(size_t)(i >> 7) * N_H + col0 + (i & 127)];
  }

  // Staging geometry: thread stages 16B; LDS row rA = tid>>2, chunk tid&3.
  const int rA = tid >> 2;
  const int kk = (tid & 3) * 8;
  const __bf16* aB = Xb + (size_t)(row0 + rA) * K_D + kk;
  const __bf16* bB = Wb + (size_t)(col0 + rA) * K_D + kk;

  // Fragment read bases, one per buffer parity (compile-time selected).
  const int lr = lane & 15;
  const int lk = (lane >> 4) * 8;
  const __bf16* aRd0 = &As[0][(wr * 64 + lr) * 32 + lk];
  const __bf16* aRd1 = &As[1][(wr * 64 + lr) * 32 + lk];
  const __bf16* bRd0 = &Bs[0][(wn * 64 + lr) * 32 + lk];
  const __bf16* bRd1 = &Bs[1][(wn * 64 + lr) * 32 + lk];

  f32x4 fin[4][4];
#pragma unroll
  for (int m = 0; m < 4; ++m)
#pragma unroll
    for (int h = 0; h < 4; ++h) fin[m][h] = (f32x4){0.f, 0.f, 0.f, 0.f};

  f32x4 acc[4][8];
#pragma unroll
  for (int m = 0; m < 4; ++m)
#pragma unroll
    for (int n = 0; n < 8; ++n) acc[m][n] = (f32x4){0.f, 0.f, 0.f, 0.f};

  // Stage k-step tn into buffer bufN. tn = pair*32 + kt;
  // pair stride in Wb = 2 experts * N_H * K_D = 1<<22 elems.
  auto STAGE = [&](int tn, int bufN) {
    const int k0 = (tn & 31) << 5;
    const size_t pOff = (size_t)(tn >> 5) << 22;
    const __bf16* a = aB + k0;
    load16_lds(a, &As[bufN][wv * 512]);
    load16_lds(a + (size_t)64 * K_D, &As[bufN][2048 + wv * 512]);
    const __bf16* b = bB + pOff + k0;
    load16_lds(b, &Bs[bufN][wv * 512]);
    load16_lds(b + (size_t)64 * K_D, &Bs[bufN][2048 + wv * 512]);
    load16_lds(b + (size_t)N_H * K_D, &Bs[bufN][4096 + wv * 512]);
    load16_lds(b + (size_t)(N_H + 64) * K_D, &Bs[bufN][6144 + wv * 512]);
  };

  // Pair epilogue: fin += g_e0*LR(acc_e0 + be) + g_e1*LR(acc_e1 + be); acc=0.
  auto EPI = [&](int p) {
    const int e0 = p * 2;
#pragma unroll
    for (int m = 0; m < 4; ++m) {
#pragma unroll
      for (int j = 0; j < 4; ++j) {
        const int r = wr * 64 + m * 16 + (lane >> 4) * 4 + j;
        const float g0 = gS[r * 8 + e0];
        const float g1 = gS[r * 8 + e0 + 1];
#pragma unroll
        for (int h = 0; h < 4; ++h) {
          const int c = wn * 64 + h * 16 + lr;
          float v0 = acc[m][h][j] + bS[e0 * 128 + c];
          v0 = (v0 >= 0.f) ? v0 : 0.01f * v0;
          float v1 = acc[m][4 + h][j] + bS[(e0 + 1) * 128 + c];
          v1 = (v1 >= 0.f) ? v1 : 0.01f * v1;
          fin[m][h][j] += g0 * v0 + g1 * v1;
        }
      }
    }
#pragma unroll
    for (int m = 0; m < 4; ++m)
#pragma unroll
      for (int n = 0; n < 8; ++n) acc[m][n] = (f32x4){0.f, 0.f, 0.f, 0.f};
  };

  // One k-step at compile-time buffer parity. doStage: t+2 <= 127.
  auto STEP = [&](int t, const __bf16* aRd, const __bf16* bRd, int bufN,
                  bool doStage, bool lastStep) {
    if (lastStep)
      asm volatile("s_waitcnt vmcnt(0)" ::: "memory");
    else
      asm volatile("s_waitcnt vmcnt(6)" ::: "memory");  // tile t landed; t+1 in flight
    __builtin_amdgcn_s_barrier();                        // all waves: tile t ready

    bf16x8 af[4], bfr[8];
#pragma unroll
    for (int m = 0; m < 4; ++m) af[m] = *(const bf16x8*)(aRd + m * 512);
#pragma unroll
    for (int n = 0; n < 8; ++n)
      bfr[n] = *(const bf16x8*)(bRd + ((n >> 2) * 128 + (n & 3) * 16) * 32);
    asm volatile("s_waitcnt lgkmcnt(0)" ::: "memory");   // frag reads retired
    __builtin_amdgcn_sched_barrier(0);                   // rule 18: pin MFMA below
    __builtin_amdgcn_s_barrier();                        // buffer bufN free

    if (doStage) STAGE(t + 2, bufN);                     // refill under MFMA

    __builtin_amdgcn_s_setprio(1);
#pragma unroll
    for (int n = 0; n < 8; ++n)
#pragma unroll
      for (int m = 0; m < 4; ++m)
        acc[m][n] = mfma16(af[m], bfr[n], acc[m][n]);
    __builtin_amdgcn_s_setprio(0);

    if ((t & 31) == 31) EPI(t >> 5);
  };

  STAGE(0, 0);
  STAGE(1, 1);  // 12 loads in flight; no drain — first STEP waits vmcnt(6)

#pragma unroll 1
  for (int t2 = 0; t2 < 126; t2 += 2) {
    STEP(t2 + 0, aRd0, bRd0, 0, true, false);
    STEP(t2 + 1, aRd1, bRd1, 1, true, false);
  }
  STEP(126, aRd0, bRd0, 0, false, false);
  STEP(127, aRd1, bRd1, 1, false, true);

  // C write (fp32 out)
#pragma unroll
  for (int m = 0; m < 4; ++m) {
#pragma unroll
    for (int j = 0; j < 4; ++j) {
      const size_t r = (size_t)(row0 + wr * 64 + m * 16 + (lane >> 4) * 4 + j);
#pragma unroll
      for (int h = 0; h < 4; ++h) {
        out[r * N_H + col0 + wn * 64 + h * 16 + lr] = fin[m][h][j];
      }
    }
  }
}

extern "C" void kernel_launch(void* const* d_in, const int* in_sizes, int n_in,
                              void* d_out, int out_size, void* d_ws, size_t ws_size,
                              hipStream_t stream) {
  const float* X  = (const float*)d_in[0];  // [8192,1024]
  const float* Wg = (const float*)d_in[1];  // [8,1024]
  const float* bg = (const float*)d_in[2];  // [8]
  const float* We = (const float*)d_in[3];  // [8,2048,1024]
  const float* be = (const float*)d_in[4];  // [8,2048]
  float* out = (float*)d_out;               // [8192,2048]

  // Workspace layout
  char* ws = (char*)d_ws;
  __bf16* Xb   = (__bf16*)(ws);                               // 16 MB
  __bf16* Wb   = (__bf16*)(ws + (size_t)16 * 1024 * 1024);    // 32 MB
  float*  gate = (float*)(ws + (size_t)48 * 1024 * 1024);     // 256 KB

  // 1) We f32 -> bf16
  cvt_kernel<<<2048, 256, 0, stream>>>(We, Wb, (N_E * N_H * K_D) / 4);

  // 2) gate probs + X f32->bf16 (fused)
  gate_kernel<<<M_TOK / 4, 256, 0, stream>>>(X, Wg, bg, gate, Xb);

  // 3) fused expert GEMM + gate-weighted reduction
  dim3 grid(M_TOK / 128, N_H / 128);
  moe_main<<<grid, 256, 0, stream>>>(Xb, Wb, gate, be, out);
}